// Round 1
// baseline (232.096 us; speedup 1.0000x reference)
//
#include <hip/hip_runtime.h>

#define T_TOK 16384
#define H 2048
#define NE 8
#define TPG 4            // tokens per wave
#define ALPHA 0.01f
#define TOPK 2

// out layout (floats): [0, 2T) idx as float, [2T, 4T) weights, [4T] aux loss
// ws layout (floats):  [0,8) sum of scores per expert, [8,16) top-k counts per expert

__global__ __launch_bounds__(256) void gate_main(
    const float* __restrict__ x, const float* __restrict__ w,
    float* __restrict__ out, float* __restrict__ ws)
{
    __shared__ float s_pi[NE];
    __shared__ float s_cnt[NE];
    const int tid = threadIdx.x;
    if (tid < NE) { s_pi[tid] = 0.f; s_cnt[tid] = 0.f; }
    __syncthreads();

    const int lane = tid & 63;
    const int wave = tid >> 6;
    const int gw   = blockIdx.x * 4 + wave;   // global wave id, [0, 4096)
    const int t0   = gw * TPG;                // first token of this wave's group

    float acc[NE][TPG];
#pragma unroll
    for (int e = 0; e < NE; e++)
#pragma unroll
        for (int t = 0; t < TPG; t++) acc[e][t] = 0.f;

    const float4* __restrict__ xv = (const float4*)x;   // 512 float4 per token
    const float4* __restrict__ wv = (const float4*)w;   // 512 float4 per expert

#pragma unroll
    for (int j = 0; j < 8; j++) {
        const int c4 = j * 64 + lane;          // float4 column index in [0,512)
        float4 xr[TPG];
#pragma unroll
        for (int t = 0; t < TPG; t++)
            xr[t] = xv[(size_t)(t0 + t) * (H / 4) + c4];
#pragma unroll
        for (int e = 0; e < NE; e++) {
            const float4 wr = wv[e * (H / 4) + c4];
#pragma unroll
            for (int t = 0; t < TPG; t++) {
                acc[e][t] = fmaf(xr[t].x, wr.x, acc[e][t]);
                acc[e][t] = fmaf(xr[t].y, wr.y, acc[e][t]);
                acc[e][t] = fmaf(xr[t].z, wr.z, acc[e][t]);
                acc[e][t] = fmaf(xr[t].w, wr.w, acc[e][t]);
            }
        }
    }

    // tree-reduce each accumulator across the 64 lanes (all lanes end with sum)
#pragma unroll
    for (int e = 0; e < NE; e++)
#pragma unroll
        for (int t = 0; t < TPG; t++) {
            float v = acc[e][t];
#pragma unroll
            for (int off = 32; off >= 1; off >>= 1)
                v += __shfl_xor(v, off, 64);
            acc[e][t] = v;
        }

    float pi_loc[NE], cnt_loc[NE];
#pragma unroll
    for (int e = 0; e < NE; e++) { pi_loc[e] = 0.f; cnt_loc[e] = 0.f; }

#pragma unroll
    for (int t = 0; t < TPG; t++) {
        float l[NE];
#pragma unroll
        for (int e = 0; e < NE; e++) l[e] = acc[e][t];
        float m = l[0];
#pragma unroll
        for (int e = 1; e < NE; e++) m = fmaxf(m, l[e]);
        float s[NE];
        float sum = 0.f;
#pragma unroll
        for (int e = 0; e < NE; e++) { s[e] = expf(l[e] - m); sum += s[e]; }
#pragma unroll
        for (int e = 0; e < NE; e++) s[e] = s[e] / sum;   // true div to match ref rounding

        // top-2, ties -> lower index (strict > scan)
        float b1 = -1.f, b2 = -1.f;
        int   i1 = 0,    i2 = 0;
#pragma unroll
        for (int e = 0; e < NE; e++) {
            if (s[e] > b1) { b2 = b1; i2 = i1; b1 = s[e]; i1 = e; }
            else if (s[e] > b2) { b2 = s[e]; i2 = e; }
        }

        if (lane == t) {
            const int tok = t0 + t;
            out[tok * 2 + 0]             = (float)i1;
            out[tok * 2 + 1]             = (float)i2;
            out[2 * T_TOK + tok * 2 + 0] = b1;
            out[2 * T_TOK + tok * 2 + 1] = b2;
        }
        const float sel = (lane == t) ? 1.f : 0.f;
#pragma unroll
        for (int e = 0; e < NE; e++) {
            pi_loc[e]  += sel * s[e];
            cnt_loc[e] += sel * (((i1 == e) ? 1.f : 0.f) + ((i2 == e) ? 1.f : 0.f));
        }
    }

    // only lanes 0..TPG-1 hold nonzero partials; fold into LDS
    if (lane < TPG) {
#pragma unroll
        for (int e = 0; e < NE; e++) {
            atomicAdd(&s_pi[e],  pi_loc[e]);
            atomicAdd(&s_cnt[e], cnt_loc[e]);
        }
    }
    __syncthreads();
    if (tid < NE) {
        atomicAdd(&ws[tid],      s_pi[tid]);
        atomicAdd(&ws[NE + tid], s_cnt[tid]);
    }
}

__global__ void gate_aux(const float* __restrict__ ws, float* __restrict__ out)
{
    if (threadIdx.x == 0) {
        float aux = 0.f;
#pragma unroll
        for (int e = 0; e < NE; e++) {
            const float Pi = ws[e] / (float)T_TOK;                    // mean score
            const float ce = ws[NE + e] / (float)(T_TOK * TOPK);      // count fraction
            aux += Pi * ce * (float)NE;
        }
        out[4 * T_TOK] = aux * ALPHA;
    }
}

extern "C" void kernel_launch(void* const* d_in, const int* in_sizes, int n_in,
                              void* d_out, int out_size, void* d_ws, size_t ws_size,
                              hipStream_t stream) {
    const float* x = (const float*)d_in[0];
    const float* w = (const float*)d_in[1];
    float* out = (float*)d_out;
    float* ws  = (float*)d_ws;

    hipMemsetAsync(ws, 0, 2 * NE * sizeof(float), stream);

    const int blocks = T_TOK / (TPG * 4);   // 4 waves/block, TPG tokens/wave -> 1024
    gate_main<<<blocks, 256, 0, stream>>>(x, w, out, ws);
    gate_aux<<<1, 64, 0, stream>>>(ws, out);
}

// Round 2
// 217.419 us; speedup vs baseline: 1.0675x; 1.0675x over previous
//
#include <hip/hip_runtime.h>

#define T_TOK 16384
#define H 2048
#define NE 8
#define TPG 4            // tokens per wave
#define ALPHA 0.01f
#define TOPK 2
#define NBLK 1024        // gate_main grid size

// out layout (floats): [0, 2T) idx as float, [2T, 4T) weights, [4T] aux loss
// ws layout (floats):  per-block partials, ws[b*16 + e] = sum(scores_e),
//                      ws[b*16 + 8 + e] = topk count_e   (b in [0,1024))

__global__ __launch_bounds__(256) void gate_main(
    const float* __restrict__ x, const float* __restrict__ w,
    float* __restrict__ out, float* __restrict__ ws)
{
    __shared__ float s_pi[NE];
    __shared__ float s_cnt[NE];
    const int tid = threadIdx.x;
    if (tid < NE) { s_pi[tid] = 0.f; s_cnt[tid] = 0.f; }
    __syncthreads();

    const int lane = tid & 63;
    const int wave = tid >> 6;
    const int gw   = blockIdx.x * 4 + wave;   // global wave id, [0, 4096)
    const int t0   = gw * TPG;                // first token of this wave's group

    float acc[NE][TPG];
#pragma unroll
    for (int e = 0; e < NE; e++)
#pragma unroll
        for (int t = 0; t < TPG; t++) acc[e][t] = 0.f;

    const float4* __restrict__ xv = (const float4*)x;   // 512 float4 per token
    const float4* __restrict__ wv = (const float4*)w;   // 512 float4 per expert

#pragma unroll
    for (int j = 0; j < 8; j++) {
        const int c4 = j * 64 + lane;          // float4 column index in [0,512)
        float4 xr[TPG];
#pragma unroll
        for (int t = 0; t < TPG; t++)
            xr[t] = xv[(size_t)(t0 + t) * (H / 4) + c4];
#pragma unroll
        for (int e = 0; e < NE; e++) {
            const float4 wr = wv[e * (H / 4) + c4];
#pragma unroll
            for (int t = 0; t < TPG; t++) {
                acc[e][t] = fmaf(xr[t].x, wr.x, acc[e][t]);
                acc[e][t] = fmaf(xr[t].y, wr.y, acc[e][t]);
                acc[e][t] = fmaf(xr[t].z, wr.z, acc[e][t]);
                acc[e][t] = fmaf(xr[t].w, wr.w, acc[e][t]);
            }
        }
    }

    // tree-reduce each accumulator across the 64 lanes (all lanes end with sum)
#pragma unroll
    for (int e = 0; e < NE; e++)
#pragma unroll
        for (int t = 0; t < TPG; t++) {
            float v = acc[e][t];
#pragma unroll
            for (int off = 32; off >= 1; off >>= 1)
                v += __shfl_xor(v, off, 64);
            acc[e][t] = v;
        }

    float pi_loc[NE], cnt_loc[NE];
#pragma unroll
    for (int e = 0; e < NE; e++) { pi_loc[e] = 0.f; cnt_loc[e] = 0.f; }

#pragma unroll
    for (int t = 0; t < TPG; t++) {
        float l[NE];
#pragma unroll
        for (int e = 0; e < NE; e++) l[e] = acc[e][t];
        float m = l[0];
#pragma unroll
        for (int e = 1; e < NE; e++) m = fmaxf(m, l[e]);
        float s[NE];
        float sum = 0.f;
#pragma unroll
        for (int e = 0; e < NE; e++) { s[e] = expf(l[e] - m); sum += s[e]; }
#pragma unroll
        for (int e = 0; e < NE; e++) s[e] = s[e] / sum;   // true div to match ref rounding

        // top-2, ties -> lower index (strict > scan)
        float b1 = -1.f, b2 = -1.f;
        int   i1 = 0,    i2 = 0;
#pragma unroll
        for (int e = 0; e < NE; e++) {
            if (s[e] > b1) { b2 = b1; i2 = i1; b1 = s[e]; i1 = e; }
            else if (s[e] > b2) { b2 = s[e]; i2 = e; }
        }

        if (lane == t) {
            const int tok = t0 + t;
            out[tok * 2 + 0]             = (float)i1;
            out[tok * 2 + 1]             = (float)i2;
            out[2 * T_TOK + tok * 2 + 0] = b1;
            out[2 * T_TOK + tok * 2 + 1] = b2;
        }
        const float sel = (lane == t) ? 1.f : 0.f;
#pragma unroll
        for (int e = 0; e < NE; e++) {
            pi_loc[e]  += sel * s[e];
            cnt_loc[e] += sel * (((i1 == e) ? 1.f : 0.f) + ((i2 == e) ? 1.f : 0.f));
        }
    }

    // only lanes 0..TPG-1 hold nonzero partials; fold into LDS (cheap, block-local)
    if (lane < TPG) {
#pragma unroll
        for (int e = 0; e < NE; e++) {
            atomicAdd(&s_pi[e],  pi_loc[e]);
            atomicAdd(&s_cnt[e], cnt_loc[e]);
        }
    }
    __syncthreads();
    // per-block partials: plain coalesced stores, NO global atomics
    if (tid < NE) {
        ws[blockIdx.x * 16 + tid]     = s_pi[tid];
        ws[blockIdx.x * 16 + 8 + tid] = s_cnt[tid];
    }
}

__global__ __launch_bounds__(256) void gate_aux(
    const float* __restrict__ ws, float* __restrict__ out)
{
    __shared__ float s_pi[NE];
    __shared__ float s_cnt[NE];
    const int tid = threadIdx.x;
    if (tid < NE) { s_pi[tid] = 0.f; s_cnt[tid] = 0.f; }
    __syncthreads();

    float pi[NE], cnt[NE];
#pragma unroll
    for (int e = 0; e < NE; e++) { pi[e] = 0.f; cnt[e] = 0.f; }

    // 1024 block-partials, 256 threads -> 4 partial records per thread
    for (int b = tid; b < NBLK; b += 256) {
        const float4* p = (const float4*)(ws + b * 16);
        float4 a0 = p[0], a1 = p[1], a2 = p[2], a3 = p[3];
        pi[0] += a0.x; pi[1] += a0.y; pi[2] += a0.z; pi[3] += a0.w;
        pi[4] += a1.x; pi[5] += a1.y; pi[6] += a1.z; pi[7] += a1.w;
        cnt[0] += a2.x; cnt[1] += a2.y; cnt[2] += a2.z; cnt[3] += a2.w;
        cnt[4] += a3.x; cnt[5] += a3.y; cnt[6] += a3.z; cnt[7] += a3.w;
    }

    // wave reduce then LDS combine (4 waves)
#pragma unroll
    for (int e = 0; e < NE; e++) {
#pragma unroll
        for (int off = 32; off >= 1; off >>= 1) {
            pi[e]  += __shfl_xor(pi[e],  off, 64);
            cnt[e] += __shfl_xor(cnt[e], off, 64);
        }
    }
    if ((tid & 63) == 0) {
#pragma unroll
        for (int e = 0; e < NE; e++) {
            atomicAdd(&s_pi[e],  pi[e]);
            atomicAdd(&s_cnt[e], cnt[e]);
        }
    }
    __syncthreads();

    if (tid == 0) {
        float aux = 0.f;
#pragma unroll
        for (int e = 0; e < NE; e++) {
            const float Pi = s_pi[e] / (float)T_TOK;                 // mean score
            const float ce = s_cnt[e] / (float)(T_TOK * TOPK);       // count fraction
            aux += Pi * ce * (float)NE;
        }
        out[4 * T_TOK] = aux * ALPHA;
    }
}

extern "C" void kernel_launch(void* const* d_in, const int* in_sizes, int n_in,
                              void* d_out, int out_size, void* d_ws, size_t ws_size,
                              hipStream_t stream) {
    const float* x = (const float*)d_in[0];
    const float* w = (const float*)d_in[1];
    float* out = (float*)d_out;
    float* ws  = (float*)d_ws;

    gate_main<<<NBLK, 256, 0, stream>>>(x, w, out, ws);
    gate_aux<<<1, 256, 0, stream>>>(ws, out);
}

// Round 3
// 203.377 us; speedup vs baseline: 1.1412x; 1.0690x over previous
//
#include <hip/hip_runtime.h>

#define T_TOK 16384
#define H 2048
#define HV (H / 4)       // float4 per row = 512
#define NE 8
#define TPG 4            // tokens per wave
#define WPB 8            // waves per block (block = 512 threads)
#define ALPHA 0.01f
#define TOPK 2
#define NBLK 512         // gate_main grid size (512 blk * 8 waves * 4 tok = 16384)

// out layout (floats): [0, 2T) idx as float, [2T, 4T) weights, [4T] aux loss
// ws layout (floats):  per-block partials, ws[b*16 + e] = sum(scores_e),
//                      ws[b*16 + 8 + e] = topk count_e   (b in [0, NBLK))

__global__ __launch_bounds__(512, 4) void gate_main(
    const float* __restrict__ x, const float* __restrict__ w,
    float* __restrict__ out, float* __restrict__ ws)
{
    __shared__ float wl[NE * H];     // 64 KB: whole gate weight, fp32
    __shared__ float s_pi[NE];
    __shared__ float s_cnt[NE];

    const int tid  = threadIdx.x;
    const int lane = tid & 63;
    const int wave = tid >> 6;
    const int t0   = (blockIdx.x * WPB + wave) * TPG;

    const float4* __restrict__ xv = (const float4*)x;
    const float4* __restrict__ wv = (const float4*)w;

    // Issue j=0 x-loads FIRST so their HBM latency hides under w staging + barrier.
    const float4* xp = xv + (size_t)t0 * HV + lane;
    float4 xa[TPG], xb[TPG];
#pragma unroll
    for (int t = 0; t < TPG; t++) xa[t] = xp[t * HV];

    // Stage w into LDS: 4096 float4 / 512 threads = 8 each, coalesced.
    float4* wl4 = (float4*)wl;
#pragma unroll
    for (int k = 0; k < 8; k++) wl4[tid + k * 512] = wv[tid + k * 512];
    if (tid < NE) { s_pi[tid] = 0.f; s_cnt[tid] = 0.f; }
    __syncthreads();

    float acc[NE][TPG];
#pragma unroll
    for (int e = 0; e < NE; e++)
#pragma unroll
        for (int t = 0; t < TPG; t++) acc[e][t] = 0.f;

    const float4* wlv = (const float4*)wl;

    // K-loop: 8 column-groups of 64 float4; x double-buffered in registers,
    // w from LDS (lgkmcnt — independent of the x vmcnt stream).
#pragma unroll
    for (int j = 0; j < 8; j += 2) {
        // prefetch j+1 into xb
#pragma unroll
        for (int t = 0; t < TPG; t++) xb[t] = xp[t * HV + (j + 1) * 64];
        // compute j from xa
#pragma unroll
        for (int e = 0; e < NE; e++) {
            const float4 wr = wlv[e * HV + j * 64 + lane];
#pragma unroll
            for (int t = 0; t < TPG; t++) {
                acc[e][t] = fmaf(xa[t].x, wr.x, acc[e][t]);
                acc[e][t] = fmaf(xa[t].y, wr.y, acc[e][t]);
                acc[e][t] = fmaf(xa[t].z, wr.z, acc[e][t]);
                acc[e][t] = fmaf(xa[t].w, wr.w, acc[e][t]);
            }
        }
        // prefetch j+2 into xa
        if (j + 2 < 8) {
#pragma unroll
            for (int t = 0; t < TPG; t++) xa[t] = xp[t * HV + (j + 2) * 64];
        }
        // compute j+1 from xb
#pragma unroll
        for (int e = 0; e < NE; e++) {
            const float4 wr = wlv[e * HV + (j + 1) * 64 + lane];
#pragma unroll
            for (int t = 0; t < TPG; t++) {
                acc[e][t] = fmaf(xb[t].x, wr.x, acc[e][t]);
                acc[e][t] = fmaf(xb[t].y, wr.y, acc[e][t]);
                acc[e][t] = fmaf(xb[t].z, wr.z, acc[e][t]);
                acc[e][t] = fmaf(xb[t].w, wr.w, acc[e][t]);
            }
        }
    }

    // tree-reduce each accumulator across the 64 lanes (all lanes end with sum)
#pragma unroll
    for (int e = 0; e < NE; e++)
#pragma unroll
        for (int t = 0; t < TPG; t++) {
            float v = acc[e][t];
#pragma unroll
            for (int off = 32; off >= 1; off >>= 1)
                v += __shfl_xor(v, off, 64);
            acc[e][t] = v;
        }

    float pi_loc[NE], cnt_loc[NE];
#pragma unroll
    for (int e = 0; e < NE; e++) { pi_loc[e] = 0.f; cnt_loc[e] = 0.f; }

#pragma unroll
    for (int t = 0; t < TPG; t++) {
        float l[NE];
#pragma unroll
        for (int e = 0; e < NE; e++) l[e] = acc[e][t];
        float m = l[0];
#pragma unroll
        for (int e = 1; e < NE; e++) m = fmaxf(m, l[e]);
        float s[NE];
        float sum = 0.f;
#pragma unroll
        for (int e = 0; e < NE; e++) { s[e] = __expf(l[e] - m); sum += s[e]; }
#pragma unroll
        for (int e = 0; e < NE; e++) s[e] = s[e] / sum;

        // top-2, ties -> lower index (strict > scan)
        float b1 = -1.f, b2 = -1.f;
        int   i1 = 0,    i2 = 0;
#pragma unroll
        for (int e = 0; e < NE; e++) {
            if (s[e] > b1) { b2 = b1; i2 = i1; b1 = s[e]; i1 = e; }
            else if (s[e] > b2) { b2 = s[e]; i2 = e; }
        }

        if (lane == t) {
            const int tok = t0 + t;
            out[tok * 2 + 0]             = (float)i1;
            out[tok * 2 + 1]             = (float)i2;
            out[2 * T_TOK + tok * 2 + 0] = b1;
            out[2 * T_TOK + tok * 2 + 1] = b2;
        }
        const float sel = (lane == t) ? 1.f : 0.f;
#pragma unroll
        for (int e = 0; e < NE; e++) {
            pi_loc[e]  += sel * s[e];
            cnt_loc[e] += sel * (((i1 == e) ? 1.f : 0.f) + ((i2 == e) ? 1.f : 0.f));
        }
    }

    // lanes 0..TPG-1 hold nonzero partials; fold into LDS (block-local)
    if (lane < TPG) {
#pragma unroll
        for (int e = 0; e < NE; e++) {
            atomicAdd(&s_pi[e],  pi_loc[e]);
            atomicAdd(&s_cnt[e], cnt_loc[e]);
        }
    }
    __syncthreads();
    // per-block partials: plain coalesced stores, NO global atomics
    if (tid < NE) {
        ws[blockIdx.x * 16 + tid]     = s_pi[tid];
        ws[blockIdx.x * 16 + 8 + tid] = s_cnt[tid];
    }
}

__global__ __launch_bounds__(256) void gate_aux(
    const float* __restrict__ ws, float* __restrict__ out)
{
    __shared__ float s_pi[NE];
    __shared__ float s_cnt[NE];
    const int tid = threadIdx.x;
    if (tid < NE) { s_pi[tid] = 0.f; s_cnt[tid] = 0.f; }
    __syncthreads();

    float pi[NE], cnt[NE];
#pragma unroll
    for (int e = 0; e < NE; e++) { pi[e] = 0.f; cnt[e] = 0.f; }

    for (int b = tid; b < NBLK; b += 256) {
        const float4* p = (const float4*)(ws + b * 16);
        float4 a0 = p[0], a1 = p[1], a2 = p[2], a3 = p[3];
        pi[0] += a0.x; pi[1] += a0.y; pi[2] += a0.z; pi[3] += a0.w;
        pi[4] += a1.x; pi[5] += a1.y; pi[6] += a1.z; pi[7] += a1.w;
        cnt[0] += a2.x; cnt[1] += a2.y; cnt[2] += a2.z; cnt[3] += a2.w;
        cnt[4] += a3.x; cnt[5] += a3.y; cnt[6] += a3.z; cnt[7] += a3.w;
    }

#pragma unroll
    for (int e = 0; e < NE; e++) {
#pragma unroll
        for (int off = 32; off >= 1; off >>= 1) {
            pi[e]  += __shfl_xor(pi[e],  off, 64);
            cnt[e] += __shfl_xor(cnt[e], off, 64);
        }
    }
    if ((tid & 63) == 0) {
#pragma unroll
        for (int e = 0; e < NE; e++) {
            atomicAdd(&s_pi[e],  pi[e]);
            atomicAdd(&s_cnt[e], cnt[e]);
        }
    }
    __syncthreads();

    if (tid == 0) {
        float aux = 0.f;
#pragma unroll
        for (int e = 0; e < NE; e++) {
            const float Pi = s_pi[e] / (float)T_TOK;
            const float ce = s_cnt[e] / (float)(T_TOK * TOPK);
            aux += Pi * ce * (float)NE;
        }
        out[4 * T_TOK] = aux * ALPHA;
    }
}

extern "C" void kernel_launch(void* const* d_in, const int* in_sizes, int n_in,
                              void* d_out, int out_size, void* d_ws, size_t ws_size,
                              hipStream_t stream) {
    const float* x = (const float*)d_in[0];
    const float* w = (const float*)d_in[1];
    float* out = (float*)d_out;
    float* ws  = (float*)d_ws;

    gate_main<<<NBLK, 512, 0, stream>>>(x, w, out, ws);
    gate_aux<<<1, 256, 0, stream>>>(ws, out);
}